// Round 4
// baseline (191.878 us; speedup 1.0000x reference)
//
#include <hip/hip_runtime.h>
#include <hip/hip_bf16.h>

typedef __attribute__((ext_vector_type(8))) unsigned short u16x8;
typedef __attribute__((ext_vector_type(8))) short short8;
typedef __attribute__((ext_vector_type(4))) float floatx4;

#define BS 64
#define CIN 256
#define II 1024
#define OO 320
#define JJ 10
#define DD 32

__device__ __forceinline__ float b2f(unsigned short u) {
    union { unsigned int i; float f; } x; x.i = ((unsigned int)u) << 16; return x.f;
}
__device__ __forceinline__ unsigned short f2b(float f) {
    union { float f; unsigned int i; } x; x.f = f;
    unsigned int r = x.i + 0x7fffu + ((x.i >> 16) & 1u);
    return (unsigned short)(r >> 16);
}

// =============== K1: fused transpose + MFMA GEMM ===============
// pred[b][o][i] = sum_c W[o][c] * x[b][c][i] + Wb[o]
// grid (8 i-chunks, 64 b), 512 threads (8 waves). Block: i-tile 128, full o=320, full K=256.
// x staged once (transposed role handled by Bs[k][i] layout + per-lane k-column frag reads).
__global__ __launch_bounds__(512) void k_gemm2(const float* __restrict__ x,
                                               const float* __restrict__ W,
                                               const float* __restrict__ Wb,
                                               unsigned short* __restrict__ pred) {
    __shared__ unsigned short Bs[CIN][132];  // [k=c][i_local], pad 4 (row 264B, 8B-aligned)
    __shared__ unsigned short As[64][264];   // [o_local][k], pad 8 (row 528B, 16B-aligned)
    __shared__ float Wb_lds[OO];

    const int i0 = blockIdx.x * 128;
    const int b  = blockIdx.y;
    const int t  = threadIdx.x, w = t >> 6, l = t & 63;

    if (t < OO) Wb_lds[t] = Wb[t];

    // ---- stage x[b][all c][i0..i0+127] f32 -> Bs[c][i] bf16 (read-once from HBM) ----
    {
        const float* xb = x + ((size_t)b * CIN) * II + i0;
        int f4 = l & 31;                 // 32 lanes cover one 128-f32 row... (128/4=32 float4)
        int rsub = l >> 5;               // 2 rows per wave-iter
        for (int q = 0; q < 16; ++q) {
            int c = q * 16 + w * 2 + rsub;
            float4 v = *(const float4*)(xb + (size_t)c * II + f4 * 4);
            unsigned short u4[4] = {f2b(v.x), f2b(v.y), f2b(v.z), f2b(v.w)};
            *(unsigned long long*)&Bs[c][f4 * 4] = *(unsigned long long*)u4;  // ds_write_b64
        }
    }
    __syncthreads();

    // ---- load B-fragments for this wave's 16 i's into registers (reused over all o) ----
    const int lm = l & 15;               // n (i) / m (o) within frag
    const int kq = (l >> 4) * 8;         // k-quad offset
    const int iloc = w * 16 + lm;        // this wave's i column
    short8 bfrag[8];
#pragma unroll
    for (int ks = 0; ks < 8; ++ks) {
        short8 f;
#pragma unroll
        for (int j = 0; j < 8; ++j) f[j] = (short)Bs[ks * 32 + kq + j][iloc];
        bfrag[ks] = f;
    }

    // ---- loop over o in 5 chunks of 64 ----
    for (int oc = 0; oc < 5; ++oc) {
        __syncthreads();  // protect As reuse
        // stage W[o-chunk] f32 -> As bf16 (L2-hot)
        {
            int r = t >> 3;              // 64 rows, 8 threads/row
            const float* wr = W + (size_t)(oc * 64 + r) * CIN;
#pragma unroll
            for (int it = 0; it < 4; ++it) {
                int c = (t & 7) * 8 + it * 64;
                float4 v0 = *(const float4*)(wr + c);
                float4 v1 = *(const float4*)(wr + c + 4);
                u16x8 u;
                u[0] = f2b(v0.x); u[1] = f2b(v0.y); u[2] = f2b(v0.z); u[3] = f2b(v0.w);
                u[4] = f2b(v1.x); u[5] = f2b(v1.y); u[6] = f2b(v1.z); u[7] = f2b(v1.w);
                *(u16x8*)&As[r][c] = u;
            }
        }
        __syncthreads();

        floatx4 acc[4] = {};
#pragma unroll
        for (int ks = 0; ks < 8; ++ks) {
#pragma unroll
            for (int mt = 0; mt < 4; ++mt) {
                short8 a = *(const short8*)&As[mt * 16 + lm][ks * 32 + kq];
                acc[mt] = __builtin_amdgcn_mfma_f32_16x16x32_bf16(a, bfrag[ks], acc[mt], 0, 0, 0);
            }
        }
        // epilogue: C col=i=lm, row=(l>>4)*4+r
#pragma unroll
        for (int mt = 0; mt < 4; ++mt) {
#pragma unroll
            for (int r = 0; r < 4; ++r) {
                int ol = mt * 16 + (l >> 4) * 4 + r;
                float val = acc[mt][r] + Wb_lds[oc * 64 + ol];
                pred[((size_t)b * OO + oc * 64 + ol) * II + i0 + iloc] = f2b(val);
            }
        }
    }
}

// =============== K2: all routing, one block per batch ===============
// 64 blocks x 1024 threads. 5 row-major sweeps of pred[b] (640KB) from L2.
__global__ __launch_bounds__(1024) void k_route_all(const unsigned short* __restrict__ pred,
                                                    float* __restrict__ out) {
    __shared__ float blog[JJ][II];        // logits accumulator (pass1 delta)
    __shared__ float cbuf[JJ][II + 8];    // delta, then c (in-place)
    __shared__ float s_lds[OO];
    __shared__ float v_lds[OO];
    __shared__ float cf[JJ];

    const int b = blockIdx.x, t = threadIdx.x, w = t >> 6, l = t & 63;
    const unsigned short* pb = pred + (size_t)b * OO * II;

    // ---- P0: s1 = 0.1 * rowsum ----
#pragma unroll 1
    for (int q = 0; q < 20; ++q) {
        int o = w * 20 + q;
        const unsigned short* row = pb + ((size_t)o << 10) + l * 8;
        u16x8 u0 = *(const u16x8*)row;
        u16x8 u1 = *(const u16x8*)(row + 512);
        float s = 0.f;
#pragma unroll
        for (int e = 0; e < 8; ++e) s += b2f(u0[e]) + b2f(u1[e]);
#pragma unroll
        for (int off = 32; off > 0; off >>= 1) s += __shfl_down(s, off);
        if (l == 0) s_lds[o] = 0.1f * s;
    }
    __syncthreads();

    for (int pass = 0; pass < 3; ++pass) {
        // ---- squash s_lds -> v_lds (or final output on pass 2) ----
        if (t < JJ) {
            float n2 = 0.f;
#pragma unroll
            for (int d = 0; d < DD; ++d) { float v = s_lds[t * DD + d]; n2 += v * v; }
            cf[t] = sqrtf(n2) / (1.0f + n2);
        }
        __syncthreads();
        if (pass == 2) {
            if (t < OO) out[b * OO + t] = s_lds[t] * cf[t >> 5];
            return;
        }
        if (t < OO) v_lds[t] = s_lds[t] * cf[t >> 5];
        __syncthreads();

        // ---- P2: delta[j][i] = sum_d v[j,d]*pred[j*32+d][i]  (waves 0..9, j=w) ----
        if (w < JJ) {
            float a0[8] = {}, a1[8] = {};
            const unsigned short* rp = pb + ((size_t)(w * DD) << 10) + l * 8;
#pragma unroll 4
            for (int d = 0; d < DD; ++d) {
                float vv = v_lds[w * DD + d];
                u16x8 u0 = *(const u16x8*)rp;
                u16x8 u1 = *(const u16x8*)(rp + 512);
#pragma unroll
                for (int e = 0; e < 8; ++e) { a0[e] += vv * b2f(u0[e]); a1[e] += vv * b2f(u1[e]); }
                rp += II;
            }
#pragma unroll
            for (int e = 0; e < 8; ++e) { cbuf[w][l * 8 + e] = a0[e]; cbuf[w][512 + l * 8 + e] = a1[e]; }
        }
        __syncthreads();

        // ---- P3: softmax over j at i=t; cbuf := c ----
        {
            float lg[JJ];
#pragma unroll
            for (int j = 0; j < JJ; ++j) {
                float dl = cbuf[j][t];
                lg[j] = (pass == 0) ? dl : blog[j][t] + dl;
            }
            if (pass == 0) {
#pragma unroll
                for (int j = 0; j < JJ; ++j) blog[j][t] = lg[j];
            }
            float m = lg[0];
#pragma unroll
            for (int j = 1; j < JJ; ++j) m = fmaxf(m, lg[j]);
            float Z = 0.f;
            float c[JJ];
#pragma unroll
            for (int j = 0; j < JJ; ++j) { c[j] = __expf(lg[j] - m); Z += c[j]; }
            float inv = 1.0f / Z;
#pragma unroll
            for (int j = 0; j < JJ; ++j) cbuf[j][t] = c[j] * inv;
        }
        __syncthreads();

        // ---- P4: s_next[j*32+d] = sum_i c[j][i]*pred[j*32+d][i]  (waves 0..9, j=w) ----
        if (w < JJ) {
            float c0[8], c1[8];
#pragma unroll
            for (int e = 0; e < 8; ++e) { c0[e] = cbuf[w][l * 8 + e]; c1[e] = cbuf[w][512 + l * 8 + e]; }
            const unsigned short* rp = pb + ((size_t)(w * DD) << 10) + l * 8;
#pragma unroll 4
            for (int d = 0; d < DD; ++d) {
                u16x8 u0 = *(const u16x8*)rp;
                u16x8 u1 = *(const u16x8*)(rp + 512);
                float s = 0.f;
#pragma unroll
                for (int e = 0; e < 8; ++e) s += c0[e] * b2f(u0[e]) + c1[e] * b2f(u1[e]);
#pragma unroll
                for (int off = 32; off > 0; off >>= 1) s += __shfl_down(s, off);
                if (l == 0) s_lds[w * DD + d] = s;
                rp += II;
            }
        }
        __syncthreads();
    }
}

extern "C" void kernel_launch(void* const* d_in, const int* in_sizes, int n_in,
                              void* d_out, int out_size, void* d_ws, size_t ws_size,
                              hipStream_t stream) {
    const float* x  = (const float*)d_in[0];  // [64][256][1024] f32
    const float* W  = (const float*)d_in[1];  // [320][256] f32
    const float* Wb = (const float*)d_in[2];  // [320] f32

    unsigned short* pred = (unsigned short*)d_ws;  // 41,943,040 B

    k_gemm2<<<dim3(8, BS), 512, 0, stream>>>(x, W, Wb, pred);
    k_route_all<<<BS, 1024, 0, stream>>>(pred, (float*)d_out);
}